// Round 4
// baseline (144.028 us; speedup 1.0000x reference)
//
#include <hip/hip_runtime.h>

// Fully-fused bior3.5 DWT, J=3, zero-padding. NBLK=8 tiles/row, 8 blocks/CU
// (100% wave occupancy), K=8 register blocking, XOR-swizzled LDS.
//
// R9 = R8 with ONE change: output stores are regular cached stores, not
// nontemporal. R8 rocprof showed WRITE_SIZE 82.3 MB vs 67.2 ideal (+22%) and
// kernel 43.9 us: the direct-from-register stores are stride-interleaved
// (thread t owns [8t,8t+8), so each wave's float4 store op writes 16B at
// every 32B). With nt (no-allocate/evict-first) those 16B partials bypass L2
// merging and reach HBM as masked sub-line writes -- write amplification +
// ~2x effective write cost. Cached stores let L2 merge the two half-line
// wave-ops into full-line writebacks. (R6's nt stores were lane-contiguous
// scalar flushes -- contiguous 256B/wave -- which is why nt was neutral there.)
//
// R7/R8 structure kept: no hi-band LDS round-trip; hi1/hi2/lo3/hi3 stored
// directly from registers, compile-time masked to owned ranges:
//   P1 stage x -> bar -> P2 L1 (lo1->LDS, hi1->global) -> bar ->
//   P3 L2 (lo2->LDS, hi2->global) -> bar -> P4 L3 (lo3,hi3->global).
// 3 barriers, c1s/c2s mult-of-4 (parity asserts enforce the R5 evenness fix).
// Kept from R6: XCD-aware (tile,row) remap, lgkm-only barriers.
//
// LDS (13.3 KB/block):
//   xs[2208]: P1-P2 staged x (+halo). P3+: lo2 [1088,1648).
//   l1[1120]: P2-P3 lo1 coeffs (pad 12).

#define FILT_LEN 12
#define ROWS  1024
#define N1    16384
#define O1    8197
#define O2    4104
#define O3    2057
#define NBLK  8
#define T1    1025
#define T2    513
#define T3    258
#define NTHR  256

#define XCAP    2208     // floats (552 float4)
#define L1CAP   1120
#define LO2_OFF 1088     // in xs; region size LO2SZ
#define LO2SZ   560

constexpr int cmin(int a, int b) { return a < b ? a : b; }
constexpr int cmax(int a, int b) { return a > b ? a : b; }

__device__ __forceinline__ int sw4(int f4) { return f4 ^ ((f4 >> 3) & 7); }
__device__ __forceinline__ float4 ld4(const float* p, int f4) {
    return reinterpret_cast<const float4*>(p)[sw4(f4)];
}
__device__ __forceinline__ void st4(float* p, int f4, float4 v) {
    reinterpret_cast<float4*>(p)[sw4(f4)] = v;
}
__device__ __forceinline__ float ldss(const float* p, int j) {
    return p[(sw4(j >> 2) << 2) | (j & 3)];
}
__device__ __forceinline__ void stss(float* p, int j, float v) {
    p[(sw4(j >> 2) << 2) | (j & 3)] = v;
}

// Barrier with LDS-only drain. __syncthreads would add vmcnt(0), stalling on
// the output global stores which nothing re-reads. All inter-phase deps here
// are through LDS (global loads are consumed by ds_write data deps before the
// barrier; compiler inserts the needed vmcnt for those).
__device__ __forceinline__ void bar_lgkm() {
    asm volatile("s_waitcnt lgkmcnt(0)" ::: "memory");
    __builtin_amdgcn_s_barrier();
    asm volatile("" ::: "memory");
}

// Regular cached output stores (R9: no nontemporal -- see header comment).
__device__ __forceinline__ void stg(float* p, float v) { *p = v; }
__device__ __forceinline__ void stg2(float* p, float a, float b) {
    *reinterpret_cast<float2*>(p) = make_float2(a, b);
}
__device__ __forceinline__ void stg4(float* p, float a, float b, float c, float d) {
    *reinterpret_cast<float4*>(p) = make_float4(a, b, c, d);
}

__device__ __forceinline__ constexpr float h0tap(int i) {
    constexpr float H[FILT_LEN] = {
        -0.013810679320049757f, 0.04143203796014927f, 0.052480581416189075f,
        -0.26792717880896527f, -0.07181553246425873f, 0.966747552403483f,
        0.966747552403483f, -0.07181553246425873f, -0.26792717880896527f,
        0.052480581416189075f, 0.04143203796014927f, -0.013810679320049757f};
    return H[i];
}
__device__ __forceinline__ constexpr float h1tap(int i) {
    return h0tap(FILT_LEN - 1 - i) * ((i & 1) ? 1.0f : -1.0f);
}

template<int B>
struct Cfg {
    static constexpr int s1 = B * T1, e1 = cmin(s1 + T1, O1);
    static constexpr int s2 = B * T2, e2 = cmin(s2 + T2, O2);
    static constexpr int s3 = B * T3, e3 = cmin(s3 + T3, O3);
    // Compute-span starts rounded DOWN to mult-of-4: keeps parity (R5 fix)
    // AND 16B-aligns the direct hi-band float4 stores (base c*s + 8*tid).
    static constexpr int c2s = cmax(0, cmin(s2, 2 * s3 - 10)) & ~3;
    static constexpr int c2e = cmin(O2, cmax(e2, 2 * e3));
    static constexpr int c1s = cmax(0, cmin(s1, 2 * c2s - 10)) & ~3;
    static constexpr int c1e = cmin(O1, cmax(e1, 2 * c2e));
    static constexpr int span1 = c1e - c1s;     // <= 1068
    static constexpr int span2 = c2e - c2s;     // <= 528
    static constexpr int span3 = e3 - s3;       // <= 258
    static constexpr int xbase = 2 * c1s - 12;  // mult of 4
    static constexpr int D2 = 2 * c2s - 10 - c1s + 12;   // even, >=0
    static constexpr int ab2 = D2 & ~3, p2 = D2 & 3;     // p2 in {0,2}
    static constexpr int D3 = 2 * s3 - 10 - c2s + 12;    // even, >=0
    static constexpr int ab3 = D3 & ~3, p3 = D3 & 3;     // p3 in {0,2}
    static constexpr int zt1 = L1CAP - (12 + span1);
    static constexpr int zt2 = LO2SZ - (12 + span2);
    static constexpr int o1s = s1 - c1s, o1e = e1 - c1s;  // owned hi1 range
    static constexpr int o2s = s2 - c2s, o2e = e2 - c2s;  // owned hi2 range

    static_assert(D2 >= 0 && D3 >= 0, "pad origin");
    static_assert((D2 & 1) == 0 && (D3 & 1) == 0, "window parity (R5 bug)");
    static_assert(p2 <= 2 && p3 <= 2, "window shift fits 28-float window");
    static_assert((c1s & 3) == 0 && (c2s & 3) == 0, "hi-band store alignment");
    static_assert((xbase & 3) == 0, "x staging alignment");
    static_assert(zt1 >= 0 && zt1 <= NTHR, "l1 tail zero in one pass");
    static_assert(zt2 >= 0 && zt2 <= NTHR, "lo2 tail zero in one pass");
    static_assert(span1 <= 8 * NTHR && span2 <= 8 * NTHR && span3 <= 8 * NTHR,
                  "single K=8 pass");
    static_assert(2 * (((span1 - 1) / 8) * 8) + 25 + 2 < XCAP, "L1 window read");
    static_assert(2 * (((span2 - 1) / 8) * 8) + ab2 + 25 + p2 < L1CAP, "L2 window read");
    static_assert(2 * (((span3 - 1) / 8) * 8) + ab3 + 25 + p3 < LO2SZ, "L3 window read");
    static_assert(o1e <= span1 && o2e <= span2, "owned range inside span");
};

template<int B>
__device__ __forceinline__ void body(
    const float* __restrict__ xrow,
    float* __restrict__ lo3r, float* __restrict__ hi1r,
    float* __restrict__ hi2r, float* __restrict__ hi3r,
    float* __restrict__ xs, float* __restrict__ l1, const int tid)
{
    using C = Cfg<B>;

    // ---------- P1: stage x (swizzled), zero l1 pads ----------
    if constexpr (C::xbase >= 0 && C::xbase + XCAP <= N1) {
        st4(xs, tid,       *reinterpret_cast<const float4*>(xrow + C::xbase + 4 * tid));
        st4(xs, tid + 256, *reinterpret_cast<const float4*>(xrow + C::xbase + 1024 + 4 * tid));
        if (tid < XCAP / 4 - 512)
            st4(xs, tid + 512, *reinterpret_cast<const float4*>(xrow + C::xbase + 2048 + 4 * tid));
    } else {
        for (int i = tid; i < XCAP / 4; i += NTHR) {
            const int g0 = C::xbase + 4 * i;
            float4 v;
            if (g0 >= 0 && g0 + 4 <= N1) {
                v = *reinterpret_cast<const float4*>(xrow + g0);
            } else {
                v.x = ((unsigned)(g0 + 0) < (unsigned)N1) ? xrow[g0 + 0] : 0.f;
                v.y = ((unsigned)(g0 + 1) < (unsigned)N1) ? xrow[g0 + 1] : 0.f;
                v.z = ((unsigned)(g0 + 2) < (unsigned)N1) ? xrow[g0 + 2] : 0.f;
                v.w = ((unsigned)(g0 + 3) < (unsigned)N1) ? xrow[g0 + 3] : 0.f;
            }
            st4(xs, i, v);
        }
    }
    if (tid < 12)      stss(l1, tid, 0.f);
    if (tid < C::zt1)  stss(l1, 12 + C::span1 + tid, 0.f);
    bar_lgkm();

    // ---------- P2: Level 1, K=8: lo1 -> LDS, hi1 -> global ----------
    {
        const int tt1 = tid * 8;
        if (tt1 < C::span1) {
            float w[28];
#pragma unroll
            for (int m = 0; m < 7; ++m) {
                const float4 v = ld4(xs, tid * 4 + m);   // logical 2*tt1 = 16*tid
                w[4 * m + 0] = v.x; w[4 * m + 1] = v.y;
                w[4 * m + 2] = v.z; w[4 * m + 3] = v.w;
            }
            float a0[8], a1[8];
#pragma unroll
            for (int k = 0; k < 8; ++k) { a0[k] = 0.f; a1[k] = 0.f; }
#pragma unroll
            for (int l = 0; l < FILT_LEN; ++l) {
#pragma unroll
                for (int k = 0; k < 8; ++k) {
                    const float v = w[2 * k + 2 + l];     // x idx 2t-10+l, base 2t-12
                    a0[k] = fmaf(v, h0tap(l), a0[k]);
                    a1[k] = fmaf(v, h1tap(l), a1[k]);
                }
            }
            if (tt1 + 8 <= C::span1) {                    // lo1 at logical 12+tt1
                st4(l1, 3 + 2 * tid, make_float4(a0[0], a0[1], a0[2], a0[3]));
                st4(l1, 4 + 2 * tid, make_float4(a0[4], a0[5], a0[6], a0[7]));
            } else {
#pragma unroll
                for (int k = 0; k < 8; ++k)
                    if (tt1 + k < C::span1) stss(l1, 12 + tt1 + k, a0[k]);
            }
            // hi1 direct from registers, masked to owned [o1s, o1e)
            if (tt1 >= C::o1s && tt1 + 8 <= C::o1e) {
                stg4(hi1r + C::c1s + tt1,     a1[0], a1[1], a1[2], a1[3]);
                stg4(hi1r + C::c1s + tt1 + 4, a1[4], a1[5], a1[6], a1[7]);
            } else {
#pragma unroll
                for (int k = 0; k < 8; ++k)
                    if (tt1 + k >= C::o1s && tt1 + k < C::o1e)
                        stg(hi1r + C::c1s + tt1 + k, a1[k]);
            }
        }
    }
    bar_lgkm();

    // ---------- P3: zero lo2 pads; Level 2: lo2 -> LDS, hi2 -> global ----------
    if (tid < 12)      stss(xs, LO2_OFF + tid, 0.f);
    if (tid < C::zt2)  stss(xs, LO2_OFF + 12 + C::span2 + tid, 0.f);
    {
        const int tt2 = tid * 8;
        if (tt2 < C::span2) {
            float w[28];
#pragma unroll
            for (int m = 0; m < 7; ++m) {   // l1 logical 2*tt2+ab2 = 16*tid+ab2
                const float4 v = ld4(l1, tid * 4 + (C::ab2 >> 2) + m);
                w[4 * m + 0] = v.x; w[4 * m + 1] = v.y;
                w[4 * m + 2] = v.z; w[4 * m + 3] = v.w;
            }
            float a0[8], a1[8];
#pragma unroll
            for (int k = 0; k < 8; ++k) { a0[k] = 0.f; a1[k] = 0.f; }
#pragma unroll
            for (int l = 0; l < FILT_LEN; ++l) {
#pragma unroll
                for (int k = 0; k < 8; ++k) {
                    const float v = w[2 * k + l + C::p2];
                    a0[k] = fmaf(v, h0tap(l), a0[k]);
                    a1[k] = fmaf(v, h1tap(l), a1[k]);
                }
            }
            if (tt2 + 8 <= C::span2) {
                // lo2 at logical LO2_OFF+12+tt2 -> f4 = 275 + 2*tid
                st4(xs, 275 + 2 * tid, make_float4(a0[0], a0[1], a0[2], a0[3]));
                st4(xs, 276 + 2 * tid, make_float4(a0[4], a0[5], a0[6], a0[7]));
            } else {
#pragma unroll
                for (int k = 0; k < 8; ++k)
                    if (tt2 + k < C::span2) stss(xs, LO2_OFF + 12 + tt2 + k, a0[k]);
            }
            // hi2 direct from registers, masked to owned [o2s, o2e)
            if (tt2 >= C::o2s && tt2 + 8 <= C::o2e) {
                stg4(hi2r + C::c2s + tt2,     a1[0], a1[1], a1[2], a1[3]);
                stg4(hi2r + C::c2s + tt2 + 4, a1[4], a1[5], a1[6], a1[7]);
            } else {
#pragma unroll
                for (int k = 0; k < 8; ++k)
                    if (tt2 + k >= C::o2s && tt2 + k < C::o2e)
                        stg(hi2r + C::c2s + tt2 + k, a1[k]);
            }
        }
    }
    bar_lgkm();

    // ---------- P4: Level 3: lo3 + hi3 direct to global ----------
    {
        const int tt3 = tid * 8;
        if (tt3 < C::span3) {
            float w[28];
#pragma unroll
            for (int m = 0; m < 7; ++m) {   // xs logical LO2_OFF+2*tt3+ab3
                const float4 v = ld4(xs, (LO2_OFF >> 2) + tid * 4 + (C::ab3 >> 2) + m);
                w[4 * m + 0] = v.x; w[4 * m + 1] = v.y;
                w[4 * m + 2] = v.z; w[4 * m + 3] = v.w;
            }
            float a0[8], a1[8];
#pragma unroll
            for (int k = 0; k < 8; ++k) { a0[k] = 0.f; a1[k] = 0.f; }
#pragma unroll
            for (int l = 0; l < FILT_LEN; ++l) {
#pragma unroll
                for (int k = 0; k < 8; ++k) {
                    const float v = w[2 * k + l + C::p3];
                    a0[k] = fmaf(v, h0tap(l), a0[k]);
                    a1[k] = fmaf(v, h1tap(l), a1[k]);
                }
            }
            if (tt3 + 8 <= C::span3) {
                if constexpr ((C::s3 & 3) == 0) {      // 16B-aligned tiles
                    stg4(lo3r + C::s3 + tt3,     a0[0], a0[1], a0[2], a0[3]);
                    stg4(lo3r + C::s3 + tt3 + 4, a0[4], a0[5], a0[6], a0[7]);
                    stg4(hi3r + C::s3 + tt3,     a1[0], a1[1], a1[2], a1[3]);
                    stg4(hi3r + C::s3 + tt3 + 4, a1[4], a1[5], a1[6], a1[7]);
                } else {                               // s3 == 2 mod 4: 8B stores
#pragma unroll
                    for (int q = 0; q < 4; ++q) {
                        stg2(lo3r + C::s3 + tt3 + 2 * q, a0[2 * q], a0[2 * q + 1]);
                        stg2(hi3r + C::s3 + tt3 + 2 * q, a1[2 * q], a1[2 * q + 1]);
                    }
                }
            } else {
#pragma unroll
                for (int k = 0; k < 8; ++k) {
                    if (tt3 + k < C::span3) {
                        stg(lo3r + C::s3 + tt3 + k, a0[k]);
                        stg(hi3r + C::s3 + tt3 + k, a1[k]);
                    }
                }
            }
        }
    }
    // no trailing barrier: kernel ends, stores drain at endpgm
}

__global__ __launch_bounds__(NTHR, 8) void dwt_fused_kernel(
    const float* __restrict__ x,
    float* __restrict__ lo3, float* __restrict__ hi1,
    float* __restrict__ hi2, float* __restrict__ hi3)
{
    __shared__ __align__(16) float xs[XCAP];
    __shared__ __align__(16) float l1[L1CAP];

    // XCD-aware remap (kept from R6): all 8 tiles of a row land on one XCD,
    // dispatch-adjacent, so inter-tile staging halos are L2 hits.
    const int tile = blockIdx.y & 7;
    const int row  = (int)blockIdx.x * 128 + ((int)blockIdx.y >> 3);
    const int tid = threadIdx.x;
    const float* xrow = x + (size_t)row * N1;
    float* lo3r = lo3 + (size_t)row * O3;
    float* hi1r = hi1 + (size_t)row * O1;
    float* hi2r = hi2 + (size_t)row * O2;
    float* hi3r = hi3 + (size_t)row * O3;

    switch (tile) {
        case 0:  body<0>(xrow, lo3r, hi1r, hi2r, hi3r, xs, l1, tid); break;
        case 1:  body<1>(xrow, lo3r, hi1r, hi2r, hi3r, xs, l1, tid); break;
        case 2:  body<2>(xrow, lo3r, hi1r, hi2r, hi3r, xs, l1, tid); break;
        case 3:  body<3>(xrow, lo3r, hi1r, hi2r, hi3r, xs, l1, tid); break;
        case 4:  body<4>(xrow, lo3r, hi1r, hi2r, hi3r, xs, l1, tid); break;
        case 5:  body<5>(xrow, lo3r, hi1r, hi2r, hi3r, xs, l1, tid); break;
        case 6:  body<6>(xrow, lo3r, hi1r, hi2r, hi3r, xs, l1, tid); break;
        default: body<7>(xrow, lo3r, hi1r, hi2r, hi3r, xs, l1, tid); break;
    }
}

extern "C" void kernel_launch(void* const* d_in, const int* in_sizes, int n_in,
                              void* d_out, int out_size, void* d_ws, size_t ws_size,
                              hipStream_t stream)
{
    const float* x = (const float*)d_in[0];
    float* out = (float*)d_out;

    // Output layout: (lo3, hi1, hi2, hi3) concatenated flat
    float* lo3 = out;
    float* hi1 = out + (size_t)ROWS * O3;
    float* hi2 = hi1 + (size_t)ROWS * O1;
    float* hi3 = hi2 + (size_t)ROWS * O2;

    dwt_fused_kernel<<<dim3(NBLK, ROWS), dim3(NTHR), 0, stream>>>(
        x, lo3, hi1, hi2, hi3);
}

// Round 5
// 120.082 us; speedup vs baseline: 1.1994x; 1.1994x over previous
//
#include <hip/hip_runtime.h>

// Fully-fused bior3.5 DWT, J=3, zero-padding. NBLK=8 tiles/row, 8 blocks/CU,
// K=8 register blocking, XOR-swizzled LDS, 4 barriers.
//
// R10 = revert to the R6 structure (best measured: 119.7 us total, kernel
// ~37 us) + ONE change: vectorized flush.
//
// Evidence trail: R8 (direct-from-register hi-band stores, nt) kernel=43.9us
// WRITE=82.3MB (+22% vs 67.2 ideal); R9 (same, cached) kernel=61.5us,
// WRITE=99.6MB, FETCH +9MB (RMW read-allocate). Root cause: direct stores are
// interleaved (thread t owns [8t,8t+8) -> each wave float4 op writes 16B at
// every 32B) AND row-misaligned (O1=8197, O3=2057 odd -> base 16B-aligned for
// only 1/4 rows) -> partial-sector writes that neither nt-combine nor cache
// cleanly. The R6 stash+flush pattern is LANE-CONTIGUOUS (wave op = solid
// block) -> full-line writebacks, clean WRITE_SIZE. So: restore stash+flush,
// but flush with ld4 (stash is f4-swizzle-aligned) + float4 contiguous global
// stores (wave = 4KB solid), scalar head/tail (<=3 elems) for the non-mult-4
// owned-range edges. lo3/hi3 flushed as float2 (s3 only guaranteed even).
//
// Kept from R6: XCD-aware (tile,row) remap, lgkm-only barriers, nt stores
// (safe for contiguous full-line writes). Cfg uses R9's &~3 rounding
// (HW-verified absmax=0 twice; parity asserts enforce the R5 evenness fix).
//
// LDS (13.3 KB/block):
//   xs[2208]: P1-P2 staged x (+halo). P3+: hi1 stash [0,span1),
//             lo2 [1088,1648), hi2 stash [1664,1664+span2).
//   l1[1120]: P2-P3 lo1 coeffs (pad 12). P4+: lo3 [0,span3), hi3 [272,..).

#define FILT_LEN 12
#define ROWS  1024
#define N1    16384
#define O1    8197
#define O2    4104
#define O3    2057
#define NBLK  8
#define T1    1025
#define T2    513
#define T3    258
#define NTHR  256

#define XCAP    2208     // floats (552 float4)
#define L1CAP   1120
#define LO2_OFF 1088     // in xs; region size LO2SZ
#define LO2SZ   560
#define HB2_OFF 1664     // in xs
#define HI3_OFF 272      // in l1

typedef float vf4 __attribute__((ext_vector_type(4)));
typedef float vf2 __attribute__((ext_vector_type(2)));

constexpr int cmin(int a, int b) { return a < b ? a : b; }
constexpr int cmax(int a, int b) { return a > b ? a : b; }

__device__ __forceinline__ int sw4(int f4) { return f4 ^ ((f4 >> 3) & 7); }
__device__ __forceinline__ float4 ld4(const float* p, int f4) {
    return reinterpret_cast<const float4*>(p)[sw4(f4)];
}
__device__ __forceinline__ void st4(float* p, int f4, float4 v) {
    reinterpret_cast<float4*>(p)[sw4(f4)] = v;
}
__device__ __forceinline__ float ldss(const float* p, int j) {
    return p[(sw4(j >> 2) << 2) | (j & 3)];
}
__device__ __forceinline__ void stss(float* p, int j, float v) {
    p[(sw4(j >> 2) << 2) | (j & 3)] = v;
}

// Barrier with LDS-only drain (R6). __syncthreads would add vmcnt(0),
// stalling on output stores nothing re-reads. All inter-phase deps are
// through LDS; global loads are consumed by ds_write data deps beforehand.
__device__ __forceinline__ void bar_lgkm() {
    asm volatile("s_waitcnt lgkmcnt(0)" ::: "memory");
    __builtin_amdgcn_s_barrier();
    asm volatile("" ::: "memory");
}

__device__ __forceinline__ void ntst(float* p, float v) {
    __builtin_nontemporal_store(v, p);
}
__device__ __forceinline__ void ntst2(float* p, float a, float b) {
    vf2 v; v.x = a; v.y = b;
    __builtin_nontemporal_store(v, reinterpret_cast<vf2*>(p));
}
__device__ __forceinline__ void ntst4(float* p, float4 u) {
    vf4 v; v.x = u.x; v.y = u.y; v.z = u.z; v.w = u.w;
    __builtin_nontemporal_store(v, reinterpret_cast<vf4*>(p));
}

// Vectorized contiguous flush: logical stash range [LO,HI) at stash offset
// SOFF (mult of 4) -> g[LO..HI). Body is ld4 + float4 nt stores (lane-
// contiguous, wave = 4KB solid); head/tail (<4 elems each) scalar.
template<int LO, int HI, int SOFF>
__device__ __forceinline__ void flushv(const float* s, float* g, const int tid) {
    static_assert((SOFF & 3) == 0, "stash offset f4-aligned");
    constexpr int A  = (LO + 3) & ~3;
    constexpr int Bq = HI & ~3;
    if (tid < A - LO)
        ntst(g + LO + tid, ldss(s, SOFF + LO + tid));
    if (tid >= 4 && tid < 4 + (HI - Bq))
        ntst(g + Bq + (tid - 4), ldss(s, SOFF + Bq + (tid - 4)));
    for (int i = A + 4 * tid; i < Bq; i += 4 * NTHR)
        ntst4(g + i, ld4(s, (SOFF + i) >> 2));
}

// float2 flush for the level-3 bands (global base only guaranteed even).
template<int HI, int SOFF>
__device__ __forceinline__ void flush2(const float* s, float* g, const int tid) {
    static_assert((SOFF & 3) == 0, "stash offset f4-aligned");
    constexpr int Bq = HI & ~1;
    for (int i = 2 * tid; i < Bq; i += 2 * NTHR) {
        const float* q = s + ((sw4((SOFF + i) >> 2) << 2) | ((SOFF + i) & 3));
        ntst2(g + i, q[0], q[1]);
    }
    if ((HI & 1) && tid == 0) ntst(g + Bq, ldss(s, SOFF + Bq));
}

__device__ __forceinline__ constexpr float h0tap(int i) {
    constexpr float H[FILT_LEN] = {
        -0.013810679320049757f, 0.04143203796014927f, 0.052480581416189075f,
        -0.26792717880896527f, -0.07181553246425873f, 0.966747552403483f,
        0.966747552403483f, -0.07181553246425873f, -0.26792717880896527f,
        0.052480581416189075f, 0.04143203796014927f, -0.013810679320049757f};
    return H[i];
}
__device__ __forceinline__ constexpr float h1tap(int i) {
    return h0tap(FILT_LEN - 1 - i) * ((i & 1) ? 1.0f : -1.0f);
}

template<int B>
struct Cfg {
    static constexpr int s1 = B * T1, e1 = cmin(s1 + T1, O1);
    static constexpr int s2 = B * T2, e2 = cmin(s2 + T2, O2);
    static constexpr int s3 = B * T3, e3 = cmin(s3 + T3, O3);
    // mult-of-4 rounding: keeps parity (R5 fix) and f4-aligns stash math.
    static constexpr int c2s = cmax(0, cmin(s2, 2 * s3 - 10)) & ~3;
    static constexpr int c2e = cmin(O2, cmax(e2, 2 * e3));
    static constexpr int c1s = cmax(0, cmin(s1, 2 * c2s - 10)) & ~3;
    static constexpr int c1e = cmin(O1, cmax(e1, 2 * c2e));
    static constexpr int span1 = c1e - c1s;     // <= ~1080
    static constexpr int span2 = c2e - c2s;     // <= ~536
    static constexpr int span3 = e3 - s3;       // <= 258
    static constexpr int xbase = 2 * c1s - 12;  // mult of 4
    static constexpr int D2 = 2 * c2s - 10 - c1s + 12;   // even, >=0
    static constexpr int ab2 = D2 & ~3, p2 = D2 & 3;     // p2 in {0,2}
    static constexpr int D3 = 2 * s3 - 10 - c2s + 12;    // even, >=0
    static constexpr int ab3 = D3 & ~3, p3 = D3 & 3;     // p3 in {0,2}
    static constexpr int zt1 = L1CAP - (12 + span1);
    static constexpr int zt2 = LO2SZ - (12 + span2);
    static constexpr int o1s = s1 - c1s, o1e = e1 - c1s;  // owned hi1 range
    static constexpr int o2s = s2 - c2s, o2e = e2 - c2s;  // owned hi2 range

    static_assert(D2 >= 0 && D3 >= 0, "pad origin");
    static_assert((D2 & 1) == 0 && (D3 & 1) == 0, "window parity (R5 bug)");
    static_assert(p2 <= 2 && p3 <= 2, "window shift fits 28-float window");
    static_assert((c1s & 3) == 0 && (c2s & 3) == 0, "span starts mult-of-4");
    static_assert((xbase & 3) == 0, "x staging alignment");
    static_assert(zt1 >= 0 && zt1 <= NTHR, "l1 tail zero in one pass");
    static_assert(zt2 >= 0 && zt2 <= NTHR, "lo2 tail zero in one pass");
    static_assert(span1 <= 8 * NTHR && span2 <= 8 * NTHR && span3 <= 8 * NTHR,
                  "single K=8 pass");
    static_assert(2 * (((span1 - 1) / 8) * 8) + 25 + 2 < XCAP, "L1 window read");
    static_assert(2 * (((span2 - 1) / 8) * 8) + ab2 + 25 + p2 < L1CAP, "L2 window read");
    static_assert(2 * (((span3 - 1) / 8) * 8) + ab3 + 25 + p3 < LO2SZ, "L3 window read");
    static_assert(span1 <= LO2_OFF, "hi1 stash fits");
    static_assert(HB2_OFF + span2 <= XCAP, "hi2 stash fits");
    static_assert(HI3_OFF + span3 <= L1CAP, "hi3 stash fits");
    static_assert(HI3_OFF >= span3, "lo3/hi3 disjoint");
    static_assert(o1e <= span1 && o2e <= span2, "owned range inside span");
};

template<int B>
__device__ __forceinline__ void body(
    const float* __restrict__ xrow,
    float* __restrict__ lo3r, float* __restrict__ hi1r,
    float* __restrict__ hi2r, float* __restrict__ hi3r,
    float* __restrict__ xs, float* __restrict__ l1, const int tid)
{
    using C = Cfg<B>;

    // ---------- P1: stage x (swizzled), zero l1 pads ----------
    if constexpr (C::xbase >= 0 && C::xbase + XCAP <= N1) {
        st4(xs, tid,       *reinterpret_cast<const float4*>(xrow + C::xbase + 4 * tid));
        st4(xs, tid + 256, *reinterpret_cast<const float4*>(xrow + C::xbase + 1024 + 4 * tid));
        if (tid < XCAP / 4 - 512)
            st4(xs, tid + 512, *reinterpret_cast<const float4*>(xrow + C::xbase + 2048 + 4 * tid));
    } else {
        for (int i = tid; i < XCAP / 4; i += NTHR) {
            const int g0 = C::xbase + 4 * i;
            float4 v;
            if (g0 >= 0 && g0 + 4 <= N1) {
                v = *reinterpret_cast<const float4*>(xrow + g0);
            } else {
                v.x = ((unsigned)(g0 + 0) < (unsigned)N1) ? xrow[g0 + 0] : 0.f;
                v.y = ((unsigned)(g0 + 1) < (unsigned)N1) ? xrow[g0 + 1] : 0.f;
                v.z = ((unsigned)(g0 + 2) < (unsigned)N1) ? xrow[g0 + 2] : 0.f;
                v.w = ((unsigned)(g0 + 3) < (unsigned)N1) ? xrow[g0 + 3] : 0.f;
            }
            st4(xs, i, v);
        }
    }
    if (tid < 12)      stss(l1, tid, 0.f);
    if (tid < C::zt1)  stss(l1, 12 + C::span1 + tid, 0.f);
    bar_lgkm();

    // ---------- P2: Level 1, K=8 (single pass): lo1 -> LDS, hi1 -> regs ----------
    float hr1[8];
    const int tt1 = tid * 8;
    if (tt1 < C::span1) {
        float w[28];
#pragma unroll
        for (int m = 0; m < 7; ++m) {
            const float4 v = ld4(xs, tid * 4 + m);   // logical 2*tt1 = 16*tid
            w[4 * m + 0] = v.x; w[4 * m + 1] = v.y;
            w[4 * m + 2] = v.z; w[4 * m + 3] = v.w;
        }
        float a0[8];
#pragma unroll
        for (int k = 0; k < 8; ++k) { a0[k] = 0.f; hr1[k] = 0.f; }
#pragma unroll
        for (int l = 0; l < FILT_LEN; ++l) {
#pragma unroll
            for (int k = 0; k < 8; ++k) {
                const float v = w[2 * k + 2 + l];     // x idx 2t-10+l, base 2t-12
                a0[k]  = fmaf(v, h0tap(l), a0[k]);
                hr1[k] = fmaf(v, h1tap(l), hr1[k]);
            }
        }
        if (tt1 + 8 <= C::span1) {                    // lo1 at logical 12+tt1
            st4(l1, 3 + 2 * tid, make_float4(a0[0], a0[1], a0[2], a0[3]));
            st4(l1, 4 + 2 * tid, make_float4(a0[4], a0[5], a0[6], a0[7]));
        } else {
#pragma unroll
            for (int k = 0; k < 8; ++k)
                if (tt1 + k < C::span1) stss(l1, 12 + tt1 + k, a0[k]);
        }
    }
    bar_lgkm();

    // ---------- P3: stash hi1; zero lo2 pads; Level 2, K=8 ----------
    if (tt1 < C::span1) {
        if (tt1 + 8 <= C::span1) {
            st4(xs, 2 * tid,     make_float4(hr1[0], hr1[1], hr1[2], hr1[3]));
            st4(xs, 2 * tid + 1, make_float4(hr1[4], hr1[5], hr1[6], hr1[7]));
        } else {
#pragma unroll
            for (int k = 0; k < 8; ++k)
                if (tt1 + k < C::span1) stss(xs, tt1 + k, hr1[k]);
        }
    }
    if (tid < 12)      stss(xs, LO2_OFF + tid, 0.f);
    if (tid < C::zt2)  stss(xs, LO2_OFF + 12 + C::span2 + tid, 0.f);

    {
        const int tt2 = tid * 8;
        if (tt2 < C::span2) {
            float w[28];
#pragma unroll
            for (int m = 0; m < 7; ++m) {   // l1 logical 2*tt2+ab2 = 16*tid+ab2
                const float4 v = ld4(l1, tid * 4 + (C::ab2 >> 2) + m);
                w[4 * m + 0] = v.x; w[4 * m + 1] = v.y;
                w[4 * m + 2] = v.z; w[4 * m + 3] = v.w;
            }
            float a0[8], a1[8];
#pragma unroll
            for (int k = 0; k < 8; ++k) { a0[k] = 0.f; a1[k] = 0.f; }
#pragma unroll
            for (int l = 0; l < FILT_LEN; ++l) {
#pragma unroll
                for (int k = 0; k < 8; ++k) {
                    const float v = w[2 * k + l + C::p2];
                    a0[k] = fmaf(v, h0tap(l), a0[k]);
                    a1[k] = fmaf(v, h1tap(l), a1[k]);
                }
            }
            if (tt2 + 8 <= C::span2) {
                // lo2 at logical LO2_OFF+12+tt2 -> f4 = 275 + 2*tid
                st4(xs, 275 + 2 * tid, make_float4(a0[0], a0[1], a0[2], a0[3]));
                st4(xs, 276 + 2 * tid, make_float4(a0[4], a0[5], a0[6], a0[7]));
                // hi2 stash at HB2_OFF+tt2 -> f4 = 416 + 2*tid
                st4(xs, 416 + 2 * tid, make_float4(a1[0], a1[1], a1[2], a1[3]));
                st4(xs, 417 + 2 * tid, make_float4(a1[4], a1[5], a1[6], a1[7]));
            } else {
#pragma unroll
                for (int k = 0; k < 8; ++k) {
                    if (tt2 + k < C::span2) {
                        stss(xs, LO2_OFF + 12 + tt2 + k, a0[k]);
                        stss(xs, HB2_OFF + tt2 + k, a1[k]);
                    }
                }
            }
        }
    }
    bar_lgkm();

    // ---------- P4: flush hi1+hi2 (vectorized); Level 3 -> stash in l1 ----------
    flushv<C::o1s, C::o1e, 0>(xs, hi1r + C::c1s, tid);
    flushv<C::o2s, C::o2e, HB2_OFF>(xs, hi2r + C::c2s, tid);

    {
        const int tt3 = tid * 8;
        if (tt3 < C::span3) {
            float w[28];
#pragma unroll
            for (int m = 0; m < 7; ++m) {   // xs logical LO2_OFF+2*tt3+ab3
                const float4 v = ld4(xs, (LO2_OFF >> 2) + tid * 4 + (C::ab3 >> 2) + m);
                w[4 * m + 0] = v.x; w[4 * m + 1] = v.y;
                w[4 * m + 2] = v.z; w[4 * m + 3] = v.w;
            }
            float a0[8], a1[8];
#pragma unroll
            for (int k = 0; k < 8; ++k) { a0[k] = 0.f; a1[k] = 0.f; }
#pragma unroll
            for (int l = 0; l < FILT_LEN; ++l) {
#pragma unroll
                for (int k = 0; k < 8; ++k) {
                    const float v = w[2 * k + l + C::p3];
                    a0[k] = fmaf(v, h0tap(l), a0[k]);
                    a1[k] = fmaf(v, h1tap(l), a1[k]);
                }
            }
            if (tt3 + 8 <= C::span3) {
                st4(l1, 2 * tid,                      make_float4(a0[0], a0[1], a0[2], a0[3]));
                st4(l1, 2 * tid + 1,                  make_float4(a0[4], a0[5], a0[6], a0[7]));
                st4(l1, (HI3_OFF >> 2) + 2 * tid,     make_float4(a1[0], a1[1], a1[2], a1[3]));
                st4(l1, (HI3_OFF >> 2) + 2 * tid + 1, make_float4(a1[4], a1[5], a1[6], a1[7]));
            } else {
#pragma unroll
                for (int k = 0; k < 8; ++k) {
                    if (tt3 + k < C::span3) {
                        stss(l1, tt3 + k, a0[k]);
                        stss(l1, HI3_OFF + tt3 + k, a1[k]);
                    }
                }
            }
        }
    }
    bar_lgkm();   // lgkm-only: the hi1/hi2 global stores above need NO drain

    // ---------- P5: flush lo3, hi3 (float2 vectorized) ----------
    flush2<C::span3, 0>(l1, lo3r + C::s3, tid);
    flush2<C::span3, HI3_OFF>(l1, hi3r + C::s3, tid);
}

__global__ __launch_bounds__(NTHR, 8) void dwt_fused_kernel(
    const float* __restrict__ x,
    float* __restrict__ lo3, float* __restrict__ hi1,
    float* __restrict__ hi2, float* __restrict__ hi3)
{
    __shared__ __align__(16) float xs[XCAP];
    __shared__ __align__(16) float l1[L1CAP];

    // XCD-aware remap (kept from R6): all 8 tiles of a row land on one XCD,
    // dispatch-adjacent, so inter-tile staging halos are L2 hits.
    const int tile = blockIdx.y & 7;
    const int row  = (int)blockIdx.x * 128 + ((int)blockIdx.y >> 3);
    const int tid = threadIdx.x;
    const float* xrow = x + (size_t)row * N1;
    float* lo3r = lo3 + (size_t)row * O3;
    float* hi1r = hi1 + (size_t)row * O1;
    float* hi2r = hi2 + (size_t)row * O2;
    float* hi3r = hi3 + (size_t)row * O3;

    switch (tile) {
        case 0:  body<0>(xrow, lo3r, hi1r, hi2r, hi3r, xs, l1, tid); break;
        case 1:  body<1>(xrow, lo3r, hi1r, hi2r, hi3r, xs, l1, tid); break;
        case 2:  body<2>(xrow, lo3r, hi1r, hi2r, hi3r, xs, l1, tid); break;
        case 3:  body<3>(xrow, lo3r, hi1r, hi2r, hi3r, xs, l1, tid); break;
        case 4:  body<4>(xrow, lo3r, hi1r, hi2r, hi3r, xs, l1, tid); break;
        case 5:  body<5>(xrow, lo3r, hi1r, hi2r, hi3r, xs, l1, tid); break;
        case 6:  body<6>(xrow, lo3r, hi1r, hi2r, hi3r, xs, l1, tid); break;
        default: body<7>(xrow, lo3r, hi1r, hi2r, hi3r, xs, l1, tid); break;
    }
}

extern "C" void kernel_launch(void* const* d_in, const int* in_sizes, int n_in,
                              void* d_out, int out_size, void* d_ws, size_t ws_size,
                              hipStream_t stream)
{
    const float* x = (const float*)d_in[0];
    float* out = (float*)d_out;

    // Output layout: (lo3, hi1, hi2, hi3) concatenated flat
    float* lo3 = out;
    float* hi1 = out + (size_t)ROWS * O3;
    float* hi2 = hi1 + (size_t)ROWS * O1;
    float* hi3 = hi2 + (size_t)ROWS * O2;

    dwt_fused_kernel<<<dim3(NBLK, ROWS), dim3(NTHR), 0, stream>>>(
        x, lo3, hi1, hi2, hi3);
}

// Round 6
// 113.597 us; speedup vs baseline: 1.2679x; 1.0571x over previous
//
#include <hip/hip_runtime.h>

// Fully-fused bior3.5 DWT, J=3, zero-padding. NBLK=8 tiles/row, 8 blocks/CU,
// K=8 register blocking, XOR-swizzled LDS, 4 barriers.
//
// R11 = R10 (kernel 43.0us, WRITE clean at 71.7MB) + ONE change: packed
// dual-FP32 FMA. rocprof: VALUBusy 38% is the largest pipe share (16.3us/CU
// of 43); 192 scalar v_fma per thread per level dominates. lo/hi bands
// multiply the SAME window value v by (h0[l], h1[l]) -> pair the (lo,hi)
// accumulators into ext_vector float2 and use __builtin_elementwise_fma ->
// llvm.fma.v2f32 -> v_pk_fma_f32 (CDNA packed math, broadcast via op_sel).
// 192 FMA issues -> 96 pk issues, BIT-IDENTICAL per-lane results (same fma,
// same tap order). Unpack at stores is free (f2 = two named VGPRs).
// Guarded by __has_builtin: fallback compiles to exactly the old scalar code.
//
// R10 write-path lesson kept: outputs go LDS-stash -> lane-contiguous
// vectorized flush (wave op = solid block -> full-line writebacks). Direct
// interleaved stores (R8/R9) amplified WRITE_SIZE 82-99MB. Kept from R6:
// XCD-aware (tile,row) remap, lgkm-only barriers, nt stores on contiguous
// flushes. Cfg &~3 rounding (HW-verified absmax=0; parity asserts = R5 fix).
//
// LDS (13.3 KB/block):
//   xs[2208]: P1-P2 staged x (+halo). P3+: hi1 stash [0,span1),
//             lo2 [1088,1648), hi2 stash [1664,1664+span2).
//   l1[1120]: P2-P3 lo1 coeffs (pad 12). P4+: lo3 [0,span3), hi3 [272,..).

#define FILT_LEN 12
#define ROWS  1024
#define N1    16384
#define O1    8197
#define O2    4104
#define O3    2057
#define NBLK  8
#define T1    1025
#define T2    513
#define T3    258
#define NTHR  256

#define XCAP    2208     // floats (552 float4)
#define L1CAP   1120
#define LO2_OFF 1088     // in xs; region size LO2SZ
#define LO2SZ   560
#define HB2_OFF 1664     // in xs
#define HI3_OFF 272      // in l1

typedef float vf4 __attribute__((ext_vector_type(4)));
typedef float vf2 __attribute__((ext_vector_type(2)));

constexpr int cmin(int a, int b) { return a < b ? a : b; }
constexpr int cmax(int a, int b) { return a > b ? a : b; }

__device__ __forceinline__ int sw4(int f4) { return f4 ^ ((f4 >> 3) & 7); }
__device__ __forceinline__ float4 ld4(const float* p, int f4) {
    return reinterpret_cast<const float4*>(p)[sw4(f4)];
}
__device__ __forceinline__ void st4(float* p, int f4, float4 v) {
    reinterpret_cast<float4*>(p)[sw4(f4)] = v;
}
__device__ __forceinline__ float ldss(const float* p, int j) {
    return p[(sw4(j >> 2) << 2) | (j & 3)];
}
__device__ __forceinline__ void stss(float* p, int j, float v) {
    p[(sw4(j >> 2) << 2) | (j & 3)] = v;
}

// Barrier with LDS-only drain (R6). __syncthreads would add vmcnt(0),
// stalling on output stores nothing re-reads. All inter-phase deps are
// through LDS; global loads are consumed by ds_write data deps beforehand.
__device__ __forceinline__ void bar_lgkm() {
    asm volatile("s_waitcnt lgkmcnt(0)" ::: "memory");
    __builtin_amdgcn_s_barrier();
    asm volatile("" ::: "memory");
}

__device__ __forceinline__ void ntst(float* p, float v) {
    __builtin_nontemporal_store(v, p);
}
__device__ __forceinline__ void ntst2(float* p, float a, float b) {
    vf2 v; v.x = a; v.y = b;
    __builtin_nontemporal_store(v, reinterpret_cast<vf2*>(p));
}
__device__ __forceinline__ void ntst4(float* p, float4 u) {
    vf4 v; v.x = u.x; v.y = u.y; v.z = u.z; v.w = u.w;
    __builtin_nontemporal_store(v, reinterpret_cast<vf4*>(p));
}

// Vectorized contiguous flush: logical stash range [LO,HI) at stash offset
// SOFF (mult of 4) -> g[LO..HI). Body is ld4 + float4 nt stores (lane-
// contiguous, wave = 4KB solid); head/tail (<4 elems each) scalar.
template<int LO, int HI, int SOFF>
__device__ __forceinline__ void flushv(const float* s, float* g, const int tid) {
    static_assert((SOFF & 3) == 0, "stash offset f4-aligned");
    constexpr int A  = (LO + 3) & ~3;
    constexpr int Bq = HI & ~3;
    if (tid < A - LO)
        ntst(g + LO + tid, ldss(s, SOFF + LO + tid));
    if (tid >= 4 && tid < 4 + (HI - Bq))
        ntst(g + Bq + (tid - 4), ldss(s, SOFF + Bq + (tid - 4)));
    for (int i = A + 4 * tid; i < Bq; i += 4 * NTHR)
        ntst4(g + i, ld4(s, (SOFF + i) >> 2));
}

// float2 flush for the level-3 bands (global base only guaranteed even).
template<int HI, int SOFF>
__device__ __forceinline__ void flush2(const float* s, float* g, const int tid) {
    static_assert((SOFF & 3) == 0, "stash offset f4-aligned");
    constexpr int Bq = HI & ~1;
    for (int i = 2 * tid; i < Bq; i += 2 * NTHR) {
        const float* q = s + ((sw4((SOFF + i) >> 2) << 2) | ((SOFF + i) & 3));
        ntst2(g + i, q[0], q[1]);
    }
    if ((HI & 1) && tid == 0) ntst(g + Bq, ldss(s, SOFF + Bq));
}

__device__ __forceinline__ constexpr float h0tap(int i) {
    constexpr float H[FILT_LEN] = {
        -0.013810679320049757f, 0.04143203796014927f, 0.052480581416189075f,
        -0.26792717880896527f, -0.07181553246425873f, 0.966747552403483f,
        0.966747552403483f, -0.07181553246425873f, -0.26792717880896527f,
        0.052480581416189075f, 0.04143203796014927f, -0.013810679320049757f};
    return H[i];
}
__device__ __forceinline__ constexpr float h1tap(int i) {
    return h0tap(FILT_LEN - 1 - i) * ((i & 1) ? 1.0f : -1.0f);
}
__device__ __forceinline__ vf2 tap2(int l) {
    vf2 t; t.x = h0tap(l); t.y = h1tap(l); return t;
}

// Packed (lo,hi) FMA core: acc[k] += (v,v) * (h0[l],h1[l]).
// Bit-identical to the scalar pair; one v_pk_fma_f32 instead of two v_fma.
__device__ __forceinline__ void pkfma(vf2& acc, float v, int l) {
#if __has_builtin(__builtin_elementwise_fma)
    vf2 vv; vv.x = v; vv.y = v;
    acc = __builtin_elementwise_fma(vv, tap2(l), acc);
#else
    acc.x = fmaf(v, h0tap(l), acc.x);
    acc.y = fmaf(v, h1tap(l), acc.y);
#endif
}

template<int B>
struct Cfg {
    static constexpr int s1 = B * T1, e1 = cmin(s1 + T1, O1);
    static constexpr int s2 = B * T2, e2 = cmin(s2 + T2, O2);
    static constexpr int s3 = B * T3, e3 = cmin(s3 + T3, O3);
    // mult-of-4 rounding: keeps parity (R5 fix) and f4-aligns stash math.
    static constexpr int c2s = cmax(0, cmin(s2, 2 * s3 - 10)) & ~3;
    static constexpr int c2e = cmin(O2, cmax(e2, 2 * e3));
    static constexpr int c1s = cmax(0, cmin(s1, 2 * c2s - 10)) & ~3;
    static constexpr int c1e = cmin(O1, cmax(e1, 2 * c2e));
    static constexpr int span1 = c1e - c1s;     // <= ~1080
    static constexpr int span2 = c2e - c2s;     // <= ~536
    static constexpr int span3 = e3 - s3;       // <= 258
    static constexpr int xbase = 2 * c1s - 12;  // mult of 4
    static constexpr int D2 = 2 * c2s - 10 - c1s + 12;   // even, >=0
    static constexpr int ab2 = D2 & ~3, p2 = D2 & 3;     // p2 in {0,2}
    static constexpr int D3 = 2 * s3 - 10 - c2s + 12;    // even, >=0
    static constexpr int ab3 = D3 & ~3, p3 = D3 & 3;     // p3 in {0,2}
    static constexpr int zt1 = L1CAP - (12 + span1);
    static constexpr int zt2 = LO2SZ - (12 + span2);
    static constexpr int o1s = s1 - c1s, o1e = e1 - c1s;  // owned hi1 range
    static constexpr int o2s = s2 - c2s, o2e = e2 - c2s;  // owned hi2 range

    static_assert(D2 >= 0 && D3 >= 0, "pad origin");
    static_assert((D2 & 1) == 0 && (D3 & 1) == 0, "window parity (R5 bug)");
    static_assert(p2 <= 2 && p3 <= 2, "window shift fits 28-float window");
    static_assert((c1s & 3) == 0 && (c2s & 3) == 0, "span starts mult-of-4");
    static_assert((xbase & 3) == 0, "x staging alignment");
    static_assert(zt1 >= 0 && zt1 <= NTHR, "l1 tail zero in one pass");
    static_assert(zt2 >= 0 && zt2 <= NTHR, "lo2 tail zero in one pass");
    static_assert(span1 <= 8 * NTHR && span2 <= 8 * NTHR && span3 <= 8 * NTHR,
                  "single K=8 pass");
    static_assert(2 * (((span1 - 1) / 8) * 8) + 25 + 2 < XCAP, "L1 window read");
    static_assert(2 * (((span2 - 1) / 8) * 8) + ab2 + 25 + p2 < L1CAP, "L2 window read");
    static_assert(2 * (((span3 - 1) / 8) * 8) + ab3 + 25 + p3 < LO2SZ, "L3 window read");
    static_assert(span1 <= LO2_OFF, "hi1 stash fits");
    static_assert(HB2_OFF + span2 <= XCAP, "hi2 stash fits");
    static_assert(HI3_OFF + span3 <= L1CAP, "hi3 stash fits");
    static_assert(HI3_OFF >= span3, "lo3/hi3 disjoint");
    static_assert(o1e <= span1 && o2e <= span2, "owned range inside span");
};

template<int B>
__device__ __forceinline__ void body(
    const float* __restrict__ xrow,
    float* __restrict__ lo3r, float* __restrict__ hi1r,
    float* __restrict__ hi2r, float* __restrict__ hi3r,
    float* __restrict__ xs, float* __restrict__ l1, const int tid)
{
    using C = Cfg<B>;

    // ---------- P1: stage x (swizzled), zero l1 pads ----------
    if constexpr (C::xbase >= 0 && C::xbase + XCAP <= N1) {
        st4(xs, tid,       *reinterpret_cast<const float4*>(xrow + C::xbase + 4 * tid));
        st4(xs, tid + 256, *reinterpret_cast<const float4*>(xrow + C::xbase + 1024 + 4 * tid));
        if (tid < XCAP / 4 - 512)
            st4(xs, tid + 512, *reinterpret_cast<const float4*>(xrow + C::xbase + 2048 + 4 * tid));
    } else {
        for (int i = tid; i < XCAP / 4; i += NTHR) {
            const int g0 = C::xbase + 4 * i;
            float4 v;
            if (g0 >= 0 && g0 + 4 <= N1) {
                v = *reinterpret_cast<const float4*>(xrow + g0);
            } else {
                v.x = ((unsigned)(g0 + 0) < (unsigned)N1) ? xrow[g0 + 0] : 0.f;
                v.y = ((unsigned)(g0 + 1) < (unsigned)N1) ? xrow[g0 + 1] : 0.f;
                v.z = ((unsigned)(g0 + 2) < (unsigned)N1) ? xrow[g0 + 2] : 0.f;
                v.w = ((unsigned)(g0 + 3) < (unsigned)N1) ? xrow[g0 + 3] : 0.f;
            }
            st4(xs, i, v);
        }
    }
    if (tid < 12)      stss(l1, tid, 0.f);
    if (tid < C::zt1)  stss(l1, 12 + C::span1 + tid, 0.f);
    bar_lgkm();

    // ---------- P2: Level 1, K=8 (single pass): lo1 -> LDS, hi1 -> regs ----------
    float hr1[8];
    const int tt1 = tid * 8;
    if (tt1 < C::span1) {
        float w[28];
#pragma unroll
        for (int m = 0; m < 7; ++m) {
            const float4 v = ld4(xs, tid * 4 + m);   // logical 2*tt1 = 16*tid
            w[4 * m + 0] = v.x; w[4 * m + 1] = v.y;
            w[4 * m + 2] = v.z; w[4 * m + 3] = v.w;
        }
        vf2 ac[8];
#pragma unroll
        for (int k = 0; k < 8; ++k) { ac[k].x = 0.f; ac[k].y = 0.f; }
#pragma unroll
        for (int l = 0; l < FILT_LEN; ++l) {
#pragma unroll
            for (int k = 0; k < 8; ++k)
                pkfma(ac[k], w[2 * k + 2 + l], l);   // x idx 2t-10+l, base 2t-12
        }
#pragma unroll
        for (int k = 0; k < 8; ++k) hr1[k] = ac[k].y;
        if (tt1 + 8 <= C::span1) {                    // lo1 at logical 12+tt1
            st4(l1, 3 + 2 * tid, make_float4(ac[0].x, ac[1].x, ac[2].x, ac[3].x));
            st4(l1, 4 + 2 * tid, make_float4(ac[4].x, ac[5].x, ac[6].x, ac[7].x));
        } else {
#pragma unroll
            for (int k = 0; k < 8; ++k)
                if (tt1 + k < C::span1) stss(l1, 12 + tt1 + k, ac[k].x);
        }
    }
    bar_lgkm();

    // ---------- P3: stash hi1; zero lo2 pads; Level 2, K=8 ----------
    if (tt1 < C::span1) {
        if (tt1 + 8 <= C::span1) {
            st4(xs, 2 * tid,     make_float4(hr1[0], hr1[1], hr1[2], hr1[3]));
            st4(xs, 2 * tid + 1, make_float4(hr1[4], hr1[5], hr1[6], hr1[7]));
        } else {
#pragma unroll
            for (int k = 0; k < 8; ++k)
                if (tt1 + k < C::span1) stss(xs, tt1 + k, hr1[k]);
        }
    }
    if (tid < 12)      stss(xs, LO2_OFF + tid, 0.f);
    if (tid < C::zt2)  stss(xs, LO2_OFF + 12 + C::span2 + tid, 0.f);

    {
        const int tt2 = tid * 8;
        if (tt2 < C::span2) {
            float w[28];
#pragma unroll
            for (int m = 0; m < 7; ++m) {   // l1 logical 2*tt2+ab2 = 16*tid+ab2
                const float4 v = ld4(l1, tid * 4 + (C::ab2 >> 2) + m);
                w[4 * m + 0] = v.x; w[4 * m + 1] = v.y;
                w[4 * m + 2] = v.z; w[4 * m + 3] = v.w;
            }
            vf2 ac[8];
#pragma unroll
            for (int k = 0; k < 8; ++k) { ac[k].x = 0.f; ac[k].y = 0.f; }
#pragma unroll
            for (int l = 0; l < FILT_LEN; ++l) {
#pragma unroll
                for (int k = 0; k < 8; ++k)
                    pkfma(ac[k], w[2 * k + l + C::p2], l);
            }
            if (tt2 + 8 <= C::span2) {
                // lo2 at logical LO2_OFF+12+tt2 -> f4 = 275 + 2*tid
                st4(xs, 275 + 2 * tid, make_float4(ac[0].x, ac[1].x, ac[2].x, ac[3].x));
                st4(xs, 276 + 2 * tid, make_float4(ac[4].x, ac[5].x, ac[6].x, ac[7].x));
                // hi2 stash at HB2_OFF+tt2 -> f4 = 416 + 2*tid
                st4(xs, 416 + 2 * tid, make_float4(ac[0].y, ac[1].y, ac[2].y, ac[3].y));
                st4(xs, 417 + 2 * tid, make_float4(ac[4].y, ac[5].y, ac[6].y, ac[7].y));
            } else {
#pragma unroll
                for (int k = 0; k < 8; ++k) {
                    if (tt2 + k < C::span2) {
                        stss(xs, LO2_OFF + 12 + tt2 + k, ac[k].x);
                        stss(xs, HB2_OFF + tt2 + k, ac[k].y);
                    }
                }
            }
        }
    }
    bar_lgkm();

    // ---------- P4: flush hi1+hi2 (vectorized); Level 3 -> stash in l1 ----------
    flushv<C::o1s, C::o1e, 0>(xs, hi1r + C::c1s, tid);
    flushv<C::o2s, C::o2e, HB2_OFF>(xs, hi2r + C::c2s, tid);

    {
        const int tt3 = tid * 8;
        if (tt3 < C::span3) {
            float w[28];
#pragma unroll
            for (int m = 0; m < 7; ++m) {   // xs logical LO2_OFF+2*tt3+ab3
                const float4 v = ld4(xs, (LO2_OFF >> 2) + tid * 4 + (C::ab3 >> 2) + m);
                w[4 * m + 0] = v.x; w[4 * m + 1] = v.y;
                w[4 * m + 2] = v.z; w[4 * m + 3] = v.w;
            }
            vf2 ac[8];
#pragma unroll
            for (int k = 0; k < 8; ++k) { ac[k].x = 0.f; ac[k].y = 0.f; }
#pragma unroll
            for (int l = 0; l < FILT_LEN; ++l) {
#pragma unroll
                for (int k = 0; k < 8; ++k)
                    pkfma(ac[k], w[2 * k + l + C::p3], l);
            }
            if (tt3 + 8 <= C::span3) {
                st4(l1, 2 * tid,                      make_float4(ac[0].x, ac[1].x, ac[2].x, ac[3].x));
                st4(l1, 2 * tid + 1,                  make_float4(ac[4].x, ac[5].x, ac[6].x, ac[7].x));
                st4(l1, (HI3_OFF >> 2) + 2 * tid,     make_float4(ac[0].y, ac[1].y, ac[2].y, ac[3].y));
                st4(l1, (HI3_OFF >> 2) + 2 * tid + 1, make_float4(ac[4].y, ac[5].y, ac[6].y, ac[7].y));
            } else {
#pragma unroll
                for (int k = 0; k < 8; ++k) {
                    if (tt3 + k < C::span3) {
                        stss(l1, tt3 + k, ac[k].x);
                        stss(l1, HI3_OFF + tt3 + k, ac[k].y);
                    }
                }
            }
        }
    }
    bar_lgkm();   // lgkm-only: the hi1/hi2 global stores above need NO drain

    // ---------- P5: flush lo3, hi3 (float2 vectorized) ----------
    flush2<C::span3, 0>(l1, lo3r + C::s3, tid);
    flush2<C::span3, HI3_OFF>(l1, hi3r + C::s3, tid);
}

__global__ __launch_bounds__(NTHR, 8) void dwt_fused_kernel(
    const float* __restrict__ x,
    float* __restrict__ lo3, float* __restrict__ hi1,
    float* __restrict__ hi2, float* __restrict__ hi3)
{
    __shared__ __align__(16) float xs[XCAP];
    __shared__ __align__(16) float l1[L1CAP];

    // XCD-aware remap (kept from R6): all 8 tiles of a row land on one XCD,
    // dispatch-adjacent, so inter-tile staging halos are L2 hits.
    const int tile = blockIdx.y & 7;
    const int row  = (int)blockIdx.x * 128 + ((int)blockIdx.y >> 3);
    const int tid = threadIdx.x;
    const float* xrow = x + (size_t)row * N1;
    float* lo3r = lo3 + (size_t)row * O3;
    float* hi1r = hi1 + (size_t)row * O1;
    float* hi2r = hi2 + (size_t)row * O2;
    float* hi3r = hi3 + (size_t)row * O3;

    switch (tile) {
        case 0:  body<0>(xrow, lo3r, hi1r, hi2r, hi3r, xs, l1, tid); break;
        case 1:  body<1>(xrow, lo3r, hi1r, hi2r, hi3r, xs, l1, tid); break;
        case 2:  body<2>(xrow, lo3r, hi1r, hi2r, hi3r, xs, l1, tid); break;
        case 3:  body<3>(xrow, lo3r, hi1r, hi2r, hi3r, xs, l1, tid); break;
        case 4:  body<4>(xrow, lo3r, hi1r, hi2r, hi3r, xs, l1, tid); break;
        case 5:  body<5>(xrow, lo3r, hi1r, hi2r, hi3r, xs, l1, tid); break;
        case 6:  body<6>(xrow, lo3r, hi1r, hi2r, hi3r, xs, l1, tid); break;
        default: body<7>(xrow, lo3r, hi1r, hi2r, hi3r, xs, l1, tid); break;
    }
}

extern "C" void kernel_launch(void* const* d_in, const int* in_sizes, int n_in,
                              void* d_out, int out_size, void* d_ws, size_t ws_size,
                              hipStream_t stream)
{
    const float* x = (const float*)d_in[0];
    float* out = (float*)d_out;

    // Output layout: (lo3, hi1, hi2, hi3) concatenated flat
    float* lo3 = out;
    float* hi1 = out + (size_t)ROWS * O3;
    float* hi2 = hi1 + (size_t)ROWS * O1;
    float* hi3 = hi2 + (size_t)ROWS * O2;

    dwt_fused_kernel<<<dim3(NBLK, ROWS), dim3(NTHR), 0, stream>>>(
        x, lo3, hi1, hi2, hi3);
}